// Round 3
// baseline (489.377 us; speedup 1.0000x reference)
//
#include <hip/hip_runtime.h>
#include <hip/hip_bf16.h>

#define LRALPHA 0.2f
#define LOG2E 1.4426950408889634f

typedef __attribute__((ext_vector_type(8))) short frag_ab;   // 8 x bf16
typedef __attribute__((ext_vector_type(4))) float frag_cd;   // 4 x f32
typedef int   iv4 __attribute__((ext_vector_type(4)));
typedef float fv4 __attribute__((ext_vector_type(4)));
typedef float fv2 __attribute__((ext_vector_type(2)));
typedef unsigned int uv4 __attribute__((ext_vector_type(4)));

static __device__ __forceinline__ unsigned short f2bf(float f) {
  __hip_bfloat16 b = __float2bfloat16(f);
  unsigned short u;
  __builtin_memcpy(&u, &b, 2);
  return u;
}

// w = truncated-bf16 exp2(max(u,0.2u)-c2), u=fma(cv,log2e,c1); Z sums the
// SAME truncated values so the softmax ratio stays an exact convex combo
// (truncation bias cancels). Pack pairs via v_perm_b32.
static __device__ __forceinline__ uv4 make_w(const iv4* ca, const fv4* cv,
                                             float c1, float c2, float& zloc) {
  uv4 out;
#pragma unroll
  for (int g = 0; g < 2; ++g) {
#pragma unroll
    for (int h = 0; h < 2; ++h) {
      unsigned b0, b1;
#pragma unroll
      for (int e = 0; e < 2; ++e) {
        const int idx = h * 2 + e;
        const float u = fmaf(cv[g][idx], LOG2E, c1);
        const float m = fmaxf(u, LRALPHA * u);
        float w = exp2f(m - c2);
        w = ca[g][idx] ? w : 0.f;
        const unsigned bb = __float_as_uint(w);
        zloc += __uint_as_float(bb & 0xFFFF0000u);  // Z of truncated w
        if (e == 0) b0 = bb; else b1 = bb;
      }
      // dword = [hi16(b1) : hi16(b0)] -> little-endian shorts {e0, e1}
      out[g * 2 + h] = __builtin_amdgcn_perm(b1, b0, 0x07060302u);
    }
  }
  return out;
}

// ---------------- Kernel A: h = X@W (fp32 via v_pk_fma), s1/s2, hT=bf16(h)^T,
// fused global s2-max via ordered-uint atomicMax.
__global__ __launch_bounds__(256, 4) void gat_hproj(
    const float* __restrict__ X, const float* __restrict__ W,
    const float* __restrict__ avec,
    float* __restrict__ s1, float* __restrict__ s2,
    unsigned* __restrict__ s2key,
    unsigned short* __restrict__ hT) {
  const int tid = threadIdx.x;
  const int row0 = blockIdx.x * 16;
  const float* Xb = X + (size_t)row0 * 256;  // wave-uniform -> s_load
  const int c = tid;

  fv2 acc2[8];  // rows (2p, 2p+1)
#pragma unroll
  for (int p = 0; p < 8; ++p) acc2[p] = (fv2){0.f, 0.f};

  for (int k = 0; k < 256; k += 4) {
    float wq[4];
#pragma unroll
    for (int i = 0; i < 4; ++i) wq[i] = W[(k + i) * 256 + c];
#pragma unroll
    for (int p = 0; p < 8; ++p) {
      const float* xr0 = Xb + (2 * p) * 256 + k;
      const float* xr1 = Xb + (2 * p + 1) * 256 + k;
#pragma unroll
      for (int i = 0; i < 4; ++i) {
        const fv2 xv = {xr0[i], xr1[i]};
        const fv2 wv = {wq[i], wq[i]};
        acc2[p] += xv * wv;  // v_pk_fma_f32
      }
    }
  }

  // hT (bf16, [f][j]): thread writes 16 contiguous bf16 in row c
  alignas(16) unsigned short hu[16];
#pragma unroll
  for (int r = 0; r < 16; ++r) hu[r] = f2bf(acc2[r >> 1][r & 1]);
  uv4* hdst = (uv4*)(hT + (size_t)c * 8192 + row0);
  hdst[0] = *(const uv4*)&hu[0];
  hdst[1] = *(const uv4*)&hu[8];

  // s1/s2 reductions over the 256 columns
  const float a1c = avec[c];
  const float a2c = avec[256 + c];
  const int lane = tid & 63, wave = tid >> 6;
  __shared__ float r1[4][16], r2[4][16];
#pragma unroll
  for (int r = 0; r < 16; ++r) {
    const float av = acc2[r >> 1][r & 1];
    float v1 = av * a1c;
    float v2 = av * a2c;
#pragma unroll
    for (int off = 32; off > 0; off >>= 1) {
      v1 += __shfl_down(v1, off);
      v2 += __shfl_down(v2, off);
    }
    if (lane == 0) { r1[wave][r] = v1; r2[wave][r] = v2; }
  }
  __syncthreads();
  if (tid < 16) {
    const float v1 = r1[0][tid] + r1[1][tid] + r1[2][tid] + r1[3][tid];
    const float v2 = r2[0][tid] + r2[1][tid] + r2[2][tid] + r2[3][tid];
    s1[row0 + tid] = v1;
    s2[row0 + tid] = v2;
    // block max of the 16 s2 values (tid<16 all in wave 0), then atomicMax
    float m = v2;
#pragma unroll
    for (int off = 8; off > 0; off >>= 1) m = fmaxf(m, __shfl_down(m, off));
    if (tid == 0) {
      const unsigned bits = __float_as_uint(m);
      const unsigned key = bits ^ ((unsigned)((int)bits >> 31) | 0x80000000u);
      atomicMax(s2key, key);  // poison 0xAAAAAAAA decodes ~+3e-13: harmless
    }
  }
}

// ---------------- Kernel B: fused masked-softmax numerator + P@h (bf16 MFMA)
// 512 blocks x 512 threads; block = 64 rows x one j-quarter (2048 cols).
// Double-buffered P, 1 barrier/iter; w(jt+1) overlaps MFMA(jt); adj 2-ahead.
__global__ __launch_bounds__(512, 4) void gat_attn(
    const int* __restrict__ adj, const unsigned short* __restrict__ hT,
    const float* __restrict__ s1, const float* __restrict__ s2,
    const unsigned* __restrict__ s2keyp,
    float* __restrict__ pacc, float* __restrict__ pZ) {
  const int bid = blockIdx.x;
  const int x = bid & 7;                       // XCD slot
  const int ks = x >> 1;                       // j-quarter pinned to XCD pair
  const int rb = ((bid >> 3) << 1) | (x & 1);  // 0..127
  const int row0 = rb * 64;
  const int jlo = ks * 2048;
  const int tid = threadIdx.x;
  const int wave = tid >> 6, lane = tid & 63;
  const int ln16 = lane & 15, quad = lane >> 4;

  __shared__ __align__(16) unsigned short P[2][64][72];  // dbuf, +8 pad
  __shared__ float Zred[64][8];

  const int r = tid >> 3, cq = tid & 7;
  const float s1r = s1[row0 + r];
  const unsigned key = s2keyp[0];
  const unsigned mb = (key & 0x80000000u) ? (key ^ 0x80000000u) : ~key;
  const float s2m = __uint_as_float(mb);
  const float tmv = s1r + s2m;
  const float mr = fmaxf(tmv, LRALPHA * tmv);  // >= row max of e
  const float c1 = s1r * LOG2E;
  const float c2 = mr * LOG2E;

  const int* adjRow = adj + (size_t)(row0 + r) * 8192 + jlo + cq * 8;
  const float* s2p = s2 + jlo + cq * 8;

  frag_cd acc[4][2];
  const frag_cd fz = {0.f, 0.f, 0.f, 0.f};
#pragma unroll
  for (int mi = 0; mi < 4; ++mi)
#pragma unroll
    for (int ni = 0; ni < 2; ++ni) acc[mi][ni] = fz;

  float zloc = 0.f;
  const int NIT = 2048 / 64;  // 32

  // preamble: w(0) -> P[0]; adj prefetch for jt=1
  {
    iv4 ca[2]; fv4 cv[2];
    ca[0] = __builtin_nontemporal_load((const iv4*)(adjRow));
    ca[1] = __builtin_nontemporal_load((const iv4*)(adjRow + 4));
    cv[0] = *(const fv4*)(s2p);
    cv[1] = *(const fv4*)(s2p + 4);
    *(uv4*)&P[0][r][cq * 8] = make_w(ca, cv, c1, c2, zloc);
  }
  iv4 a[2];
  a[0] = __builtin_nontemporal_load((const iv4*)(adjRow + 64));
  a[1] = __builtin_nontemporal_load((const iv4*)(adjRow + 68));
  __syncthreads();

  for (int jt = 0; jt < NIT; ++jt) {
    const int cur = jt & 1, nxt = cur ^ 1;
    const size_t jbase = (size_t)(jlo + jt * 64);

    // B-fragments for THIS iter — issue first (L2 latency under w-compute)
    frag_ab bf[2][2];
#pragma unroll
    for (int kk = 0; kk < 2; ++kk)
#pragma unroll
      for (int ni = 0; ni < 2; ++ni) {
        const int f = wave * 32 + ni * 16 + ln16;
        bf[kk][ni] = *(const frag_ab*)(hT + (size_t)f * 8192 + jbase + kk * 32 + quad * 8);
      }

    // adj prefetch for jt+2 (HBM latency ~900 cyc)
    iv4 a2[2];
    if (jt + 2 < NIT) {
      const int o = (jt + 2) * 64;
      a2[0] = __builtin_nontemporal_load((const iv4*)(adjRow + o));
      a2[1] = __builtin_nontemporal_load((const iv4*)(adjRow + o + 4));
    }

    // w(jt+1) -> P[nxt]; s2 loaded at use (8 KB slice, L1-hot)
    if (jt + 1 < NIT) {
      const int o = (jt + 1) * 64;
      fv4 cv[2];
      cv[0] = *(const fv4*)(s2p + o);
      cv[1] = *(const fv4*)(s2p + o + 4);
      *(uv4*)&P[nxt][r][cq * 8] = make_w(a, cv, c1, c2, zloc);
    }

    // A-frags from P[cur] + MFMA
#pragma unroll
    for (int kk = 0; kk < 2; ++kk) {
      frag_ab af[4];
#pragma unroll
      for (int mi = 0; mi < 4; ++mi)
        af[mi] = *(const frag_ab*)&P[cur][mi * 16 + ln16][kk * 32 + quad * 8];
#pragma unroll
      for (int mi = 0; mi < 4; ++mi)
#pragma unroll
        for (int ni = 0; ni < 2; ++ni)
          acc[mi][ni] = __builtin_amdgcn_mfma_f32_16x16x32_bf16(
              af[mi], bf[kk][ni], acc[mi][ni], 0, 0, 0);
    }
    __syncthreads();
    a[0] = a2[0]; a[1] = a2[1];
  }

  // Z partial reduce + store
  Zred[r][cq] = zloc;
  __syncthreads();
  if (tid < 64) {
    float z = 0.f;
#pragma unroll
    for (int q = 0; q < 8; ++q) z += Zred[tid][q];
    pZ[ks * 8192 + row0 + tid] = z;
  }

  // numerator partials (C/D layout: col=lane&15, row=quad*4+reg)
  float* paccb = pacc + ((size_t)ks * 8192 + row0) * 256;
#pragma unroll
  for (int mi = 0; mi < 4; ++mi) {
#pragma unroll
    for (int ni = 0; ni < 2; ++ni) {
      const int f = wave * 32 + ni * 16 + ln16;
#pragma unroll
      for (int reg = 0; reg < 4; ++reg) {
        const int grow = mi * 16 + quad * 4 + reg;
        __builtin_nontemporal_store(acc[mi][ni][reg], paccb + (size_t)grow * 256 + f);
      }
    }
  }
}

// ---------------- Kernel C: combine 4 k-split partials, divide by Z, elu
__global__ __launch_bounds__(256) void gat_combine(
    const float* __restrict__ pacc, const float* __restrict__ pZ,
    float* __restrict__ out) {
  const int idx = blockIdx.x * 256 + threadIdx.x;  // float4 index
  const int row = idx >> 6;
  const float z = pZ[row] + pZ[8192 + row] + pZ[16384 + row] + pZ[24576 + row];
  const float invz = 1.f / z;
  const size_t PSTRIDE = (size_t)8192 * 256;
  const fv4 n0 = *(const fv4*)(pacc + (size_t)idx * 4);
  const fv4 n1 = *(const fv4*)(pacc + PSTRIDE + (size_t)idx * 4);
  const fv4 n2 = *(const fv4*)(pacc + 2 * PSTRIDE + (size_t)idx * 4);
  const fv4 n3 = *(const fv4*)(pacc + 3 * PSTRIDE + (size_t)idx * 4);
  fv4 o;
#pragma unroll
  for (int e = 0; e < 4; ++e) {
    const float vsum = (n0[e] + n1[e]) + (n2[e] + n3[e]);
    const float vv = vsum * invz;
    o[e] = vv > 0.f ? vv : expm1f(vv);
  }
  *(fv4*)(out + (size_t)idx * 4) = o;
}

extern "C" void kernel_launch(void* const* d_in, const int* in_sizes, int n_in,
                              void* d_out, int out_size, void* d_ws, size_t ws_size,
                              hipStream_t stream) {
  const float* X = (const float*)d_in[0];
  const int* adj = (const int*)d_in[1];
  const float* W = (const float*)d_in[2];
  const float* avec = (const float*)d_in[3];
  float* out = (float*)d_out;

  float* wsf = (float*)d_ws;
  float* s1 = wsf;                         // 8192
  float* s2 = wsf + 8192;                  // 8192
  unsigned* s2key = (unsigned*)(wsf + 16384);  // 1 (atomicMax over poison: OK)
  float* pZ = wsf + 24576;                 // 4*8192
  float* pacc = wsf + 65536;               // 4*8192*256 floats (32 MB)
  unsigned short* hT = (unsigned short*)(wsf + 65536 + 4 * 8192 * 256);  // 4 MB

  hipLaunchKernelGGL(gat_hproj, dim3(512), dim3(256), 0, stream, X, W, avec, s1, s2, s2key, hT);
  hipLaunchKernelGGL(gat_attn, dim3(512), dim3(512), 0, stream, adj, hT, s1, s2, s2key, pacc, pZ);
  hipLaunchKernelGGL(gat_combine, dim3(2048), dim3(256), 0, stream, pacc, pZ, out);
}